// Round 8
// baseline (194.655 us; speedup 1.0000x reference)
//
#include <hip/hip_runtime.h>
#include <stdint.h>

typedef int   i32x4 __attribute__((ext_vector_type(4)));
typedef float f32x4 __attribute__((ext_vector_type(4)));

// ---------------- workspace layout (bytes) ----------------
#define WS_PART    0                         // 1536 floats: per-block absmax partials
#define WS_XQ      32768                     // 4 MB  int8 swizzled [32][16][4][128][16]
#define WS_W1QT    (WS_XQ   + 4096*1024)     // 4 MB  w1^T swizzled [32][16][4][128][16]
#define WS_W2QT    (WS_W1QT + 4096*1024)     // 4 MB  w2^T swizzled [8][64][4][128][16]
#define WS_PS      (WS_W2QT + 4096*1024)     // 16 MB plane_s swizzled [32][64][4][128][16]
#define WS_PH      (WS_PS   + 4096*4096)     // 16 MB plane_h

__device__ __forceinline__ void async16(const void* g, void* l) {
  __builtin_amdgcn_global_load_lds(
      (const __attribute__((address_space(1))) unsigned*)g,
      (__attribute__((address_space(3))) unsigned*)l, 16, 0, 0);
}

// block-wide absmax over p0[0..n0) and optional p1[0..n1); bit-exact in any order
__device__ __forceinline__ float block_absmax(const float* __restrict__ p0, int n0,
                                              const float* __restrict__ p1, int n1,
                                              float* red, float* slot) {
  int tid = threadIdx.x, nt = blockDim.x;
  float m = 0.f;
  for (int i = tid; i < n0; i += nt) m = fmaxf(m, fabsf(p0[i]));
  if (p1) for (int i = tid; i < n1; i += nt) m = fmaxf(m, fabsf(p1[i]));
  for (int off = 32; off; off >>= 1) m = fmaxf(m, __shfl_down(m, off));
  if ((tid & 63) == 0) red[tid >> 6] = m;
  __syncthreads();
  if (tid == 0) {
    int nw = nt >> 6;
    float M = red[0];
    for (int w = 1; w < nw; w++) M = fmaxf(M, red[w]);
    *slot = M;
  }
  __syncthreads();
  return *slot;
}

// ---------------- abs-max partials over x, w1f, w2f ----------------
__global__ void k_absmax3(const float* __restrict__ x, const float* __restrict__ w1,
                          const float* __restrict__ w2, float* __restrict__ part) {
  int seg = blockIdx.x >> 9;              // 0,1,2
  int b = blockIdx.x & 511;
  const float* p = (seg == 0) ? x : (seg == 1) ? w1 : w2;
  int i = b * 256 + threadIdx.x;
  float m = 0.f;
  #pragma unroll
  for (int it = 0; it < 8; it++) {
    f32x4 v = ((const f32x4*)p)[i + it * 131072];
    m = fmaxf(m, fmaxf(fmaxf(fabsf(v.x), fabsf(v.y)), fmaxf(fabsf(v.z), fabsf(v.w))));
  }
  for (int off = 32; off; off >>= 1) m = fmaxf(m, __shfl_down(m, off));
  __shared__ float red[4];
  if ((threadIdx.x & 63) == 0) red[threadIdx.x >> 6] = m;
  __syncthreads();
  if (threadIdx.x == 0)
    part[blockIdx.x] = fmaxf(fmaxf(red[0], red[1]), fmaxf(red[2], red[3]));
}

// ---------------- quantize + transpose a weight matrix (inline body) ----------------
__device__ __forceinline__ void quantT_body(const float* __restrict__ w, float s,
                                            i32x4* __restrict__ out, int C, int tkbits,
                                            int b) {
  int L = b * 256 + threadIdx.x;
  int h_in = L & 127;
  int kb = (L >> 7) & 3;
  int tk = (L >> 9) & ((1 << tkbits) - 1);
  int hblk = L >> (9 + tkbits);
  int h = hblk * 128 + h_in;
  int k0 = (tk * 4 + kb) * 16;
  int wd[4];
  #pragma unroll
  for (int d = 0; d < 4; d++) {
    unsigned acc = 0;
    #pragma unroll
    for (int j = 0; j < 4; j++) {
      float v = w[(size_t)(k0 + d * 4 + j) * C + h];
      int q = (int)rintf(v / s) & 255;
      acc |= (unsigned)q << (8 * j);
    }
    wd[d] = (int)acc;
  }
  i32x4 o; o.x = wd[0]; o.y = wd[1]; o.z = wd[2]; o.w = wd[3];
  out[L] = o;
}

// ---------------- fused prep: quant_x + quantT(w1) + quantT(w2) ----------------
__global__ void k_prep(const float* __restrict__ x, const float* __restrict__ w1f,
                       const float* __restrict__ w2f, const float* __restrict__ b1f,
                       const float* __restrict__ b2f, const float* __restrict__ part,
                       i32x4* __restrict__ xq, i32x4* __restrict__ w1qt,
                       i32x4* __restrict__ w2qt) {
  __shared__ float red[4];
  __shared__ float slot;
  int seg = blockIdx.x >> 10;             // block-uniform
  int b = blockIdx.x & 1023;
  if (seg == 0) {
    float s = block_absmax(part, 512, nullptr, 0, red, &slot) / 127.0f;
    int L = b * 256 + threadIdx.x;
    int m_in = L & 127, kb = (L >> 7) & 3, tk = (L >> 9) & 15, mblk = L >> 13;
    int m = mblk * 128 + m_in;
    int k0 = (tk * 4 + kb) * 16;
    const f32x4* px = (const f32x4*)(x + m * 1024 + k0);
    int wd[4];
    #pragma unroll
    for (int d = 0; d < 4; d++) {
      f32x4 v = px[d];
      int b0 = (int)rintf(v.x / s) & 255;
      int b1 = (int)rintf(v.y / s) & 255;
      int b2 = (int)rintf(v.z / s) & 255;
      int b3 = (int)rintf(v.w / s) & 255;
      wd[d] = b0 | (b1 << 8) | (b2 << 16) | (b3 << 24);
    }
    i32x4 o; o.x = wd[0]; o.y = wd[1]; o.z = wd[2]; o.w = wd[3];
    xq[L] = o;
  } else if (seg == 1) {
    float s = block_absmax(part + 512, 512, b1f, 4096, red, &slot) / 127.0f;
    quantT_body(w1f, s, w1qt, 4096, 4, b);
  } else {
    float s = block_absmax(part + 1024, 512, b2f, 1024, red, &slot) / 127.0f;
    quantT_body(w2f, s, w2qt, 1024, 6, b);
  }
}

// ---------------- GEMM1 v2: LDS-free (both operands L2-resident, global->reg) ----------------
// Both w1qt (4 MB) and xq (4 MB) live in L2/L3; the old LDS round-trip (16 KB/block/step
// through 32-bank LDS + 2 barriers/step) was the measured bottleneck (~2050 of 2150
// cyc/block-step, MfmaUtil 11%). Direct global->VGPR frags, 1-deep register prefetch,
// no barriers in the K-loop. Index-identical to the staged path by construction.
__launch_bounds__(256)
__global__ void k_gemm1(const i32x4* __restrict__ Aq, const i32x4* __restrict__ Bq,
                        const float* __restrict__ part, const float* __restrict__ b1f,
                        unsigned* __restrict__ plane_s, unsigned* __restrict__ plane_h) {
  __shared__ float red[4];
  __shared__ float slot;
  __shared__ int b1s[128];
  int tid = threadIdx.x;
  int bb = blockIdx.x;   // batch block, 0..31
  int hb = blockIdx.y;   // H block,    0..31
  int lane = tid & 63, wid = tid >> 6;
  int wm = wid & 1, wn = wid >> 1;
  int g = lane >> 4, l15 = lane & 15;

  const i32x4* gA = Aq + (size_t)hb * 16 * 512;
  const i32x4* gB = Bq + (size_t)bb * 16 * 512;
  int aoff = g * 128 + wm * 64 + l15;   // + r*16
  int boff = g * 128 + wn * 64 + l15;   // + c*16

  // recompute scales from partials (bit-identical across kernels)
  float sx  = block_absmax(part, 512, nullptr, 0, red, &slot) / 127.0f;
  float s1v = block_absmax(part + 512, 512, b1f, 4096, red, &slot) / 127.0f;
  float mult1 = sx * s1v / s1v;   // exact f32 expr as reference
  for (int i = tid; i < 128; i += 256)
    b1s[i] = (int)rintf(b1f[hb * 128 + i] / s1v);
  __syncthreads();   // b1s ready (no other barriers before epilogue reads it)

  i32x4 acc[4][4];
  #pragma unroll
  for (int r = 0; r < 4; r++)
    #pragma unroll
    for (int c = 0; c < 4; c++) acc[r][c] = (i32x4)(0);

  // prologue: frags for t=0
  i32x4 af[4], bf[4];
  #pragma unroll
  for (int r = 0; r < 4; r++) af[r] = gA[aoff + r * 16];
  #pragma unroll
  for (int c = 0; c < 4; c++) bf[c] = gB[boff + c * 16];

  for (int t = 0; t < 15; ++t) {
    // prefetch t+1 (issues before the MFMA cluster; waitcnt lands at the rotate)
    i32x4 an[4], bn[4];
    const i32x4* ga = gA + (t + 1) * 512;
    const i32x4* gb = gB + (t + 1) * 512;
    #pragma unroll
    for (int r = 0; r < 4; r++) an[r] = ga[aoff + r * 16];
    #pragma unroll
    for (int c = 0; c < 4; c++) bn[c] = gb[boff + c * 16];
    #pragma unroll
    for (int r = 0; r < 4; r++)
      #pragma unroll
      for (int c = 0; c < 4; c++)
        acc[r][c] = __builtin_amdgcn_mfma_i32_16x16x64_i8(af[r], bf[c], acc[r][c], 0, 0, 0);
    #pragma unroll
    for (int r = 0; r < 4; r++) { af[r] = an[r]; bf[r] = bn[r]; }
  }
  // final K-step
  #pragma unroll
  for (int r = 0; r < 4; r++)
    #pragma unroll
    for (int c = 0; c < 4; c++)
      acc[r][c] = __builtin_amdgcn_mfma_i32_16x16x64_i8(af[r], bf[c], acc[r][c], 0, 0, 0);

  int t2base = hb * 2 + wm;
  #pragma unroll
  for (int r = 0; r < 4; r++) {
    int hloc = wm * 64 + r * 16 + 4 * g;
    int bq0 = b1s[hloc], bq1 = b1s[hloc + 1], bq2 = b1s[hloc + 2], bq3 = b1s[hloc + 3];
    #pragma unroll
    for (int c = 0; c < 4; c++) {
      unsigned lo = 0, hi = 0;
      #pragma unroll
      for (int q = 0; q < 4; q++) {
        int y0 = acc[r][c][q];
        int bqv = (q == 0) ? bq0 : (q == 1) ? bq1 : (q == 2) ? bq2 : bq3;
        int o = (short)((int)rintf((float)y0 * mult1) + bqv);    // int16 semantics
        int a = o > 0 ? o : 0;                                   // relu
        int s8 = (int)(signed char)(a & 0xFF);
        int h8 = (a >> 8) + (s8 < 0 ? 1 : 0);                    // a = 256*h8 + s8
        lo |= (unsigned)(s8 & 0xFF) << (8 * q);
        hi |= (unsigned)(h8 & 0xFF) << (8 * q);
      }
      int m_in = wn * 64 + c * 16 + l15;
      unsigned idx = (((unsigned)(bb * 64 + t2base) * 512u + (unsigned)(r * 128 + m_in)) << 2) + g;
      plane_s[idx] = lo;
      plane_h[idx] = hi;
    }
  }
}

// ---------------- GEMM2 v5: 64x128 tile, split-K2, A-only LDS (32KB), B via L2->regs ----------------
// Proven 16-wave/CU skeleton (512 blocks x 512 thr, 2-buf, block-wide sync, LDS merge).
// Delta vs round-0: B fragments load global->VGPR directly (coalesced, single-buffered,
// issued after the MFMA cluster so L2 latency hides under barrier + A ds_reads).
__launch_bounds__(512, 4)
__global__ void k_gemm2(const i32x4* __restrict__ Ps, const i32x4* __restrict__ Ph,
                        const i32x4* __restrict__ Bq, const float* __restrict__ part,
                        const float* __restrict__ b1f, const float* __restrict__ b2f,
                        float* __restrict__ out) {
  __shared__ i32x4 st[2048];   // 32 KB: [kh][buf][ AsS 0-255 | AsH 256-511 ]
  __shared__ float red[8];
  __shared__ float slot;

  int tid = threadIdx.x;
  int L = blockIdx.x;
  int mb = ((L & 7) << 3) | ((L >> 3) & 7);   // same mb -> same XCD (A-strip L2 reuse)
  int nb = L >> 6;                             // 0..7
  int mblk = mb >> 1, half = mb & 1;
  int wid = tid >> 6, lane = tid & 63;
  int kh = wid >> 2, w2 = wid & 3;
  int wm = w2 & 1, wn = w2 >> 1;
  int g = lane >> 4, l15 = lane & 15;
  int t256 = tid & 255;
  int sbase = kh * 1024;
  int a_idx = (t256 >> 6) * 128 + half * 64 + (t256 & 63);
  int b_idx = g * 128 + wn * 64 + l15;         // + c*16 within B chunk

  // prefetch tt=0 A-planes into buf 0 of this kh pipeline
  {
    int t = kh * 32;
    const i32x4* pS = Ps + ((size_t)(mblk * 64 + t) << 9);
    const i32x4* pH = Ph + ((size_t)(mblk * 64 + t) << 9);
    async16(pS + a_idx, &st[sbase + t256]);
    async16(pH + a_idx, &st[sbase + 256 + t256]);
  }
  // B(tt=0) fragments: direct global->reg (w2qt is L2-resident)
  i32x4 bf[4];
  {
    const i32x4* pB = Bq + ((size_t)(nb * 64 + kh * 32) << 9);
    #pragma unroll
    for (int c = 0; c < 4; c++) bf[c] = pB[b_idx + c * 16];
  }

  // scales (overlaps tile-0 load latency)
  float s1v = block_absmax(part + 512, 512, b1f, 4096, red, &slot) / 127.0f;
  float s2v = block_absmax(part + 1024, 512, b2f, 1024, red, &slot) / 127.0f;
  float mult2 = s1v * s2v / s2v;   // exact f32 expr as reference
  int bq[4];
  #pragma unroll
  for (int c = 0; c < 4; c++)
    bq[c] = (int)rintf(b2f[nb * 128 + wn * 64 + c * 16 + l15] / s2v);

  i32x4 accS[2][4], accH[2][4];
  #pragma unroll
  for (int r = 0; r < 2; r++)
    #pragma unroll
    for (int c = 0; c < 4; c++) { accS[r][c] = (i32x4)(0); accH[r][c] = (i32x4)(0); }

  for (int tt = 0; tt < 32; ++tt) {
    int cur = tt & 1;
    __syncthreads();
    if (tt + 1 < 32) {
      int t = kh * 32 + tt + 1;
      const i32x4* pS = Ps + ((size_t)(mblk * 64 + t) << 9);
      const i32x4* pH = Ph + ((size_t)(mblk * 64 + t) << 9);
      int R1 = sbase + (cur ^ 1) * 512;
      async16(pS + a_idx, &st[R1 + t256]);
      async16(pH + a_idx, &st[R1 + 256 + t256]);
    }
    int R = sbase + cur * 512;
    i32x4 aS[2], aH[2];
    #pragma unroll
    for (int r = 0; r < 2; r++) {
      aS[r] = st[R + g * 64 + wm * 32 + r * 16 + l15];
      aH[r] = st[R + 256 + g * 64 + wm * 32 + r * 16 + l15];
    }
    #pragma unroll
    for (int r = 0; r < 2; r++)
      #pragma unroll
      for (int c = 0; c < 4; c++) {
        accS[r][c] = __builtin_amdgcn_mfma_i32_16x16x64_i8(aS[r], bf[c], accS[r][c], 0, 0, 0);
        accH[r][c] = __builtin_amdgcn_mfma_i32_16x16x64_i8(aH[r], bf[c], accH[r][c], 0, 0, 0);
      }
    // load next tile's B fragments after their last use (hides L2 latency
    // under the barrier + A ds_reads of the next iteration)
    if (tt + 1 < 32) {
      const i32x4* pB = Bq + ((size_t)(nb * 64 + kh * 32 + tt + 1) << 9);
      #pragma unroll
      for (int c = 0; c < 4; c++) bf[c] = pB[b_idx + c * 16];
    }
  }

  // combine planes within this k-half (exact mod 2^32)
  int y0p[2][4][4];
  #pragma unroll
  for (int r = 0; r < 2; r++)
    #pragma unroll
    for (int c = 0; c < 4; c++)
      #pragma unroll
      for (int q = 0; q < 4; q++)
        y0p[r][c][q] = accS[r][c][q] + accH[r][c][q] * 256;

  __syncthreads();                 // staging LDS now dead; reuse as merge buffer
  int* mg = (int*)st;              // 32 KB: [idx32][t256]
  if (kh == 1) {
    #pragma unroll
    for (int r = 0; r < 2; r++)
      #pragma unroll
      for (int c = 0; c < 4; c++)
        #pragma unroll
        for (int q = 0; q < 4; q++)
          mg[((r * 4 + c) * 4 + q) * 256 + t256] = y0p[r][c][q];
  }
  __syncthreads();
  if (kh == 0) {
    #pragma unroll
    for (int r = 0; r < 2; r++) {
      int m0 = mb * 64 + wm * 32 + r * 16 + 4 * g;
      #pragma unroll
      for (int c = 0; c < 4; c++) {
        int n = nb * 128 + wn * 64 + c * 16 + l15;
        #pragma unroll
        for (int q = 0; q < 4; q++) {
          int y0 = y0p[r][c][q] + mg[((r * 4 + c) * 4 + q) * 256 + t256];
          int o = (short)((int)rintf((float)y0 * mult2) + bq[c]);   // int16 semantics
          out[(size_t)(m0 + q) * 1024 + n] = (float)o * s2v;
        }
      }
    }
  }
}

extern "C" void kernel_launch(void* const* d_in, const int* in_sizes, int n_in,
                              void* d_out, int out_size, void* d_ws, size_t ws_size,
                              hipStream_t stream) {
  const float* x   = (const float*)d_in[0];
  const float* w1f = (const float*)d_in[1];
  const float* b1f = (const float*)d_in[2];
  const float* w2f = (const float*)d_in[3];
  const float* b2f = (const float*)d_in[4];
  float* out = (float*)d_out;

  char* ws = (char*)d_ws;
  float*  part    = (float*)(ws + WS_PART);
  i32x4*  xq      = (i32x4*)(ws + WS_XQ);
  i32x4*  w1qt    = (i32x4*)(ws + WS_W1QT);
  i32x4*  w2qt    = (i32x4*)(ws + WS_W2QT);
  unsigned* ps    = (unsigned*)(ws + WS_PS);
  unsigned* ph    = (unsigned*)(ws + WS_PH);

  k_absmax3<<<1536, 256, 0, stream>>>(x, w1f, w2f, part);
  k_prep<<<3072, 256, 0, stream>>>(x, w1f, w2f, b1f, b2f, part, xq, w1qt, w2qt);
  k_gemm1<<<dim3(32, 32), 256, 0, stream>>>(w1qt, xq, part, b1f, ps, ph);
  k_gemm2<<<512, 512, 0, stream>>>((const i32x4*)ps, (const i32x4*)ph, w2qt,
                                   part, b1f, b2f, out);
}

// Round 9
// 183.891 us; speedup vs baseline: 1.0585x; 1.0585x over previous
//
#include <hip/hip_runtime.h>
#include <stdint.h>

typedef int   i32x4 __attribute__((ext_vector_type(4)));
typedef float f32x4 __attribute__((ext_vector_type(4)));

// ---------------- workspace layout (bytes) ----------------
#define WS_PART    0                         // 1536 floats: absmax partials; [1536..1538] = scales s_x, s_1, s_2
#define WS_XQ      32768                     // 4 MB  int8 swizzled [32][16][4][128][16]
#define WS_W1QT    (WS_XQ   + 4096*1024)     // 4 MB  w1^T swizzled [32][16][4][128][16]
#define WS_W2QT    (WS_W1QT + 4096*1024)     // 4 MB  w2^T swizzled [8][64][4][128][16]
#define WS_PS      (WS_W2QT + 4096*1024)     // 16 MB plane_s swizzled [32][64][4][128][16]
#define WS_PH      (WS_PS   + 4096*4096)     // 16 MB plane_h

__device__ __forceinline__ void async16(const void* g, void* l) {
  __builtin_amdgcn_global_load_lds(
      (const __attribute__((address_space(1))) unsigned*)g,
      (__attribute__((address_space(3))) unsigned*)l, 16, 0, 0);
}

// block-wide absmax over p0[0..n0) and optional p1[0..n1); bit-exact in any order
__device__ __forceinline__ float block_absmax(const float* __restrict__ p0, int n0,
                                              const float* __restrict__ p1, int n1,
                                              float* red, float* slot) {
  int tid = threadIdx.x, nt = blockDim.x;
  float m = 0.f;
  for (int i = tid; i < n0; i += nt) m = fmaxf(m, fabsf(p0[i]));
  if (p1) for (int i = tid; i < n1; i += nt) m = fmaxf(m, fabsf(p1[i]));
  for (int off = 32; off; off >>= 1) m = fmaxf(m, __shfl_down(m, off));
  if ((tid & 63) == 0) red[tid >> 6] = m;
  __syncthreads();
  if (tid == 0) {
    int nw = nt >> 6;
    float M = red[0];
    for (int w = 1; w < nw; w++) M = fmaxf(M, red[w]);
    *slot = M;
  }
  __syncthreads();
  return *slot;
}

// ---------------- abs-max partials over x, w1f, w2f ----------------
__global__ void k_absmax3(const float* __restrict__ x, const float* __restrict__ w1,
                          const float* __restrict__ w2, float* __restrict__ part) {
  int seg = blockIdx.x >> 9;              // 0,1,2
  int b = blockIdx.x & 511;
  const float* p = (seg == 0) ? x : (seg == 1) ? w1 : w2;
  int i = b * 256 + threadIdx.x;
  float m = 0.f;
  #pragma unroll
  for (int it = 0; it < 8; it++) {
    f32x4 v = ((const f32x4*)p)[i + it * 131072];
    m = fmaxf(m, fmaxf(fmaxf(fabsf(v.x), fabsf(v.y)), fmaxf(fabsf(v.z), fabsf(v.w))));
  }
  for (int off = 32; off; off >>= 1) m = fmaxf(m, __shfl_down(m, off));
  __shared__ float red[4];
  if ((threadIdx.x & 63) == 0) red[threadIdx.x >> 6] = m;
  __syncthreads();
  if (threadIdx.x == 0)
    part[blockIdx.x] = fmaxf(fmaxf(red[0], red[1]), fmaxf(red[2], red[3]));
}

// ---------------- quantize + transpose a weight matrix (inline body) ----------------
__device__ __forceinline__ void quantT_body(const float* __restrict__ w, float s,
                                            i32x4* __restrict__ out, int C, int tkbits,
                                            int b) {
  int L = b * 256 + threadIdx.x;
  int h_in = L & 127;
  int kb = (L >> 7) & 3;
  int tk = (L >> 9) & ((1 << tkbits) - 1);
  int hblk = L >> (9 + tkbits);
  int h = hblk * 128 + h_in;
  int k0 = (tk * 4 + kb) * 16;
  int wd[4];
  #pragma unroll
  for (int d = 0; d < 4; d++) {
    unsigned acc = 0;
    #pragma unroll
    for (int j = 0; j < 4; j++) {
      float v = w[(size_t)(k0 + d * 4 + j) * C + h];
      int q = (int)rintf(v / s) & 255;
      acc |= (unsigned)q << (8 * j);
    }
    wd[d] = (int)acc;
  }
  i32x4 o; o.x = wd[0]; o.y = wd[1]; o.z = wd[2]; o.w = wd[3];
  out[L] = o;
}

// ---------------- fused prep: quant_x + quantT(w1) + quantT(w2) + scale handoff ----------------
__global__ void k_prep(const float* __restrict__ x, const float* __restrict__ w1f,
                       const float* __restrict__ w2f, const float* __restrict__ b1f,
                       const float* __restrict__ b2f, const float* __restrict__ part,
                       float* __restrict__ scales,
                       i32x4* __restrict__ xq, i32x4* __restrict__ w1qt,
                       i32x4* __restrict__ w2qt) {
  __shared__ float red[4];
  __shared__ float slot;
  int seg = blockIdx.x >> 10;             // block-uniform
  int b = blockIdx.x & 1023;
  if (seg == 0) {
    float s = block_absmax(part, 512, nullptr, 0, red, &slot) / 127.0f;
    if (b == 0 && threadIdx.x == 0) scales[0] = s;   // handoff (bit-identical everywhere)
    int L = b * 256 + threadIdx.x;
    int m_in = L & 127, kb = (L >> 7) & 3, tk = (L >> 9) & 15, mblk = L >> 13;
    int m = mblk * 128 + m_in;
    int k0 = (tk * 4 + kb) * 16;
    const f32x4* px = (const f32x4*)(x + m * 1024 + k0);
    int wd[4];
    #pragma unroll
    for (int d = 0; d < 4; d++) {
      f32x4 v = px[d];
      int b0 = (int)rintf(v.x / s) & 255;
      int b1 = (int)rintf(v.y / s) & 255;
      int b2 = (int)rintf(v.z / s) & 255;
      int b3 = (int)rintf(v.w / s) & 255;
      wd[d] = b0 | (b1 << 8) | (b2 << 16) | (b3 << 24);
    }
    i32x4 o; o.x = wd[0]; o.y = wd[1]; o.z = wd[2]; o.w = wd[3];
    xq[L] = o;
  } else if (seg == 1) {
    float s = block_absmax(part + 512, 512, b1f, 4096, red, &slot) / 127.0f;
    if (b == 0 && threadIdx.x == 0) scales[1] = s;
    quantT_body(w1f, s, w1qt, 4096, 4, b);
  } else {
    float s = block_absmax(part + 1024, 512, b2f, 1024, red, &slot) / 127.0f;
    if (b == 0 && threadIdx.x == 0) scales[2] = s;
    quantT_body(w2f, s, w2qt, 1024, 6, b);
  }
}

// ---------------- GEMM1 v3: 1-wave blocks, LDS/barrier-free, scales from prep ----------------
// Round-8 measured: LDS-free at 256-thr blocks = 50.8 us, MfmaUtil 12%, ~6 waves/CU —
// latency-bound. Fix occupancy: 64-thr blocks (grid 32x32x4), no barriers/LDS at all,
// scales loaded from prep's handoff (kills the 4.6K-element scan + 2 barrier phases).
// Fragment indexing identical to v2 (same wm/wn decode, now from blockIdx.z).
__launch_bounds__(64)
__global__ void k_gemm1(const i32x4* __restrict__ Aq, const i32x4* __restrict__ Bq,
                        const float* __restrict__ scales, const float* __restrict__ b1f,
                        unsigned* __restrict__ plane_s, unsigned* __restrict__ plane_h) {
  int lane = threadIdx.x;               // 0..63
  int bb = blockIdx.x;                  // batch block, 0..31
  int hb = blockIdx.y;                  // H block,     0..31
  int wid = blockIdx.z;                 // 0..3 (was wave id)
  int wm = wid & 1, wn = wid >> 1;
  int g = lane >> 4, l15 = lane & 15;

  const i32x4* gA = Aq + (size_t)hb * 16 * 512;
  const i32x4* gB = Bq + (size_t)bb * 16 * 512;
  int aoff = g * 128 + wm * 64 + l15;   // + r*16
  int boff = g * 128 + wn * 64 + l15;   // + c*16

  float sx  = scales[0];
  float s1v = scales[1];
  float mult1 = sx * s1v / s1v;         // exact f32 expr as reference

  i32x4 acc[4][4];
  #pragma unroll
  for (int r = 0; r < 4; r++)
    #pragma unroll
    for (int c = 0; c < 4; c++) acc[r][c] = (i32x4)(0);

  // prologue: frags for t=0
  i32x4 af[4], bf[4];
  #pragma unroll
  for (int r = 0; r < 4; r++) af[r] = gA[aoff + r * 16];
  #pragma unroll
  for (int c = 0; c < 4; c++) bf[c] = gB[boff + c * 16];

  for (int t = 0; t < 15; ++t) {
    i32x4 an[4], bn[4];
    const i32x4* ga = gA + (t + 1) * 512;
    const i32x4* gb = gB + (t + 1) * 512;
    #pragma unroll
    for (int r = 0; r < 4; r++) an[r] = ga[aoff + r * 16];
    #pragma unroll
    for (int c = 0; c < 4; c++) bn[c] = gb[boff + c * 16];
    #pragma unroll
    for (int r = 0; r < 4; r++)
      #pragma unroll
      for (int c = 0; c < 4; c++)
        acc[r][c] = __builtin_amdgcn_mfma_i32_16x16x64_i8(af[r], bf[c], acc[r][c], 0, 0, 0);
    #pragma unroll
    for (int r = 0; r < 4; r++) { af[r] = an[r]; bf[r] = bn[r]; }
  }
  #pragma unroll
  for (int r = 0; r < 4; r++)
    #pragma unroll
    for (int c = 0; c < 4; c++)
      acc[r][c] = __builtin_amdgcn_mfma_i32_16x16x64_i8(af[r], bf[c], acc[r][c], 0, 0, 0);

  int t2base = hb * 2 + wm;
  #pragma unroll
  for (int r = 0; r < 4; r++) {
    int hloc = wm * 64 + r * 16 + 4 * g;
    // per-lane bias requant (was LDS b1s[]) — same rintf(b1f/s1v) values
    int bq0 = (int)rintf(b1f[hb * 128 + hloc + 0] / s1v);
    int bq1 = (int)rintf(b1f[hb * 128 + hloc + 1] / s1v);
    int bq2 = (int)rintf(b1f[hb * 128 + hloc + 2] / s1v);
    int bq3 = (int)rintf(b1f[hb * 128 + hloc + 3] / s1v);
    #pragma unroll
    for (int c = 0; c < 4; c++) {
      unsigned lo = 0, hi = 0;
      #pragma unroll
      for (int q = 0; q < 4; q++) {
        int y0 = acc[r][c][q];
        int bqv = (q == 0) ? bq0 : (q == 1) ? bq1 : (q == 2) ? bq2 : bq3;
        int o = (short)((int)rintf((float)y0 * mult1) + bqv);    // int16 semantics
        int a = o > 0 ? o : 0;                                   // relu
        int s8 = (int)(signed char)(a & 0xFF);
        int h8 = (a >> 8) + (s8 < 0 ? 1 : 0);                    // a = 256*h8 + s8
        lo |= (unsigned)(s8 & 0xFF) << (8 * q);
        hi |= (unsigned)(h8 & 0xFF) << (8 * q);
      }
      int m_in = wn * 64 + c * 16 + l15;
      unsigned idx = (((unsigned)(bb * 64 + t2base) * 512u + (unsigned)(r * 128 + m_in)) << 2) + g;
      plane_s[idx] = lo;
      plane_h[idx] = hi;
    }
  }
}

// ---------------- GEMM2 v5: 64x128 tile, split-K2, A-only LDS (32KB), B via L2->regs ----------------
// (unchanged this round)
__launch_bounds__(512, 4)
__global__ void k_gemm2(const i32x4* __restrict__ Ps, const i32x4* __restrict__ Ph,
                        const i32x4* __restrict__ Bq, const float* __restrict__ part,
                        const float* __restrict__ b1f, const float* __restrict__ b2f,
                        float* __restrict__ out) {
  __shared__ i32x4 st[2048];   // 32 KB: [kh][buf][ AsS 0-255 | AsH 256-511 ]
  __shared__ float red[8];
  __shared__ float slot;

  int tid = threadIdx.x;
  int L = blockIdx.x;
  int mb = ((L & 7) << 3) | ((L >> 3) & 7);   // same mb -> same XCD (A-strip L2 reuse)
  int nb = L >> 6;                             // 0..7
  int mblk = mb >> 1, half = mb & 1;
  int wid = tid >> 6, lane = tid & 63;
  int kh = wid >> 2, w2 = wid & 3;
  int wm = w2 & 1, wn = w2 >> 1;
  int g = lane >> 4, l15 = lane & 15;
  int t256 = tid & 255;
  int sbase = kh * 1024;
  int a_idx = (t256 >> 6) * 128 + half * 64 + (t256 & 63);
  int b_idx = g * 128 + wn * 64 + l15;         // + c*16 within B chunk

  // prefetch tt=0 A-planes into buf 0 of this kh pipeline
  {
    int t = kh * 32;
    const i32x4* pS = Ps + ((size_t)(mblk * 64 + t) << 9);
    const i32x4* pH = Ph + ((size_t)(mblk * 64 + t) << 9);
    async16(pS + a_idx, &st[sbase + t256]);
    async16(pH + a_idx, &st[sbase + 256 + t256]);
  }
  // B(tt=0) fragments: direct global->reg (w2qt is L2-resident)
  i32x4 bf[4];
  {
    const i32x4* pB = Bq + ((size_t)(nb * 64 + kh * 32) << 9);
    #pragma unroll
    for (int c = 0; c < 4; c++) bf[c] = pB[b_idx + c * 16];
  }

  // scales (overlaps tile-0 load latency)
  float s1v = block_absmax(part + 512, 512, b1f, 4096, red, &slot) / 127.0f;
  float s2v = block_absmax(part + 1024, 512, b2f, 1024, red, &slot) / 127.0f;
  float mult2 = s1v * s2v / s2v;   // exact f32 expr as reference
  int bq[4];
  #pragma unroll
  for (int c = 0; c < 4; c++)
    bq[c] = (int)rintf(b2f[nb * 128 + wn * 64 + c * 16 + l15] / s2v);

  i32x4 accS[2][4], accH[2][4];
  #pragma unroll
  for (int r = 0; r < 2; r++)
    #pragma unroll
    for (int c = 0; c < 4; c++) { accS[r][c] = (i32x4)(0); accH[r][c] = (i32x4)(0); }

  for (int tt = 0; tt < 32; ++tt) {
    int cur = tt & 1;
    __syncthreads();
    if (tt + 1 < 32) {
      int t = kh * 32 + tt + 1;
      const i32x4* pS = Ps + ((size_t)(mblk * 64 + t) << 9);
      const i32x4* pH = Ph + ((size_t)(mblk * 64 + t) << 9);
      int R1 = sbase + (cur ^ 1) * 512;
      async16(pS + a_idx, &st[R1 + t256]);
      async16(pH + a_idx, &st[R1 + 256 + t256]);
    }
    int R = sbase + cur * 512;
    i32x4 aS[2], aH[2];
    #pragma unroll
    for (int r = 0; r < 2; r++) {
      aS[r] = st[R + g * 64 + wm * 32 + r * 16 + l15];
      aH[r] = st[R + 256 + g * 64 + wm * 32 + r * 16 + l15];
    }
    #pragma unroll
    for (int r = 0; r < 2; r++)
      #pragma unroll
      for (int c = 0; c < 4; c++) {
        accS[r][c] = __builtin_amdgcn_mfma_i32_16x16x64_i8(aS[r], bf[c], accS[r][c], 0, 0, 0);
        accH[r][c] = __builtin_amdgcn_mfma_i32_16x16x64_i8(aH[r], bf[c], accH[r][c], 0, 0, 0);
      }
    // load next tile's B fragments after their last use (hides L2 latency
    // under the barrier + A ds_reads of the next iteration)
    if (tt + 1 < 32) {
      const i32x4* pB = Bq + ((size_t)(nb * 64 + kh * 32 + tt + 1) << 9);
      #pragma unroll
      for (int c = 0; c < 4; c++) bf[c] = pB[b_idx + c * 16];
    }
  }

  // combine planes within this k-half (exact mod 2^32)
  int y0p[2][4][4];
  #pragma unroll
  for (int r = 0; r < 2; r++)
    #pragma unroll
    for (int c = 0; c < 4; c++)
      #pragma unroll
      for (int q = 0; q < 4; q++)
        y0p[r][c][q] = accS[r][c][q] + accH[r][c][q] * 256;

  __syncthreads();                 // staging LDS now dead; reuse as merge buffer
  int* mg = (int*)st;              // 32 KB: [idx32][t256]
  if (kh == 1) {
    #pragma unroll
    for (int r = 0; r < 2; r++)
      #pragma unroll
      for (int c = 0; c < 4; c++)
        #pragma unroll
        for (int q = 0; q < 4; q++)
          mg[((r * 4 + c) * 4 + q) * 256 + t256] = y0p[r][c][q];
  }
  __syncthreads();
  if (kh == 0) {
    #pragma unroll
    for (int r = 0; r < 2; r++) {
      int m0 = mb * 64 + wm * 32 + r * 16 + 4 * g;
      #pragma unroll
      for (int c = 0; c < 4; c++) {
        int n = nb * 128 + wn * 64 + c * 16 + l15;
        #pragma unroll
        for (int q = 0; q < 4; q++) {
          int y0 = y0p[r][c][q] + mg[((r * 4 + c) * 4 + q) * 256 + t256];
          int o = (short)((int)rintf((float)y0 * mult2) + bq[c]);   // int16 semantics
          out[(size_t)(m0 + q) * 1024 + n] = (float)o * s2v;
        }
      }
    }
  }
}

extern "C" void kernel_launch(void* const* d_in, const int* in_sizes, int n_in,
                              void* d_out, int out_size, void* d_ws, size_t ws_size,
                              hipStream_t stream) {
  const float* x   = (const float*)d_in[0];
  const float* w1f = (const float*)d_in[1];
  const float* b1f = (const float*)d_in[2];
  const float* w2f = (const float*)d_in[3];
  const float* b2f = (const float*)d_in[4];
  float* out = (float*)d_out;

  char* ws = (char*)d_ws;
  float*  part    = (float*)(ws + WS_PART);
  float*  scales  = part + 1536;
  i32x4*  xq      = (i32x4*)(ws + WS_XQ);
  i32x4*  w1qt    = (i32x4*)(ws + WS_W1QT);
  i32x4*  w2qt    = (i32x4*)(ws + WS_W2QT);
  unsigned* ps    = (unsigned*)(ws + WS_PS);
  unsigned* ph    = (unsigned*)(ws + WS_PH);

  k_absmax3<<<1536, 256, 0, stream>>>(x, w1f, w2f, part);
  k_prep<<<3072, 256, 0, stream>>>(x, w1f, w2f, b1f, b2f, part, scales, xq, w1qt, w2qt);
  k_gemm1<<<dim3(32, 32, 4), 64, 0, stream>>>(w1qt, xq, scales, b1f, ps, ph);
  k_gemm2<<<512, 512, 0, stream>>>((const i32x4*)ps, (const i32x4*)ph, w2qt,
                                   part, b1f, b2f, out);
}

// Round 11
// 174.562 us; speedup vs baseline: 1.1151x; 1.0534x over previous
//
#include <hip/hip_runtime.h>
#include <stdint.h>

typedef int   i32x4 __attribute__((ext_vector_type(4)));
typedef float f32x4 __attribute__((ext_vector_type(4)));

// ---------------- workspace layout (bytes) ----------------
#define WS_PART    0                         // 1536 floats: absmax partials; [1536..1538] = scales s_x, s_1, s_2
#define WS_XQ      32768                     // 4 MB  int8 swizzled [32][16][4][128][16]
#define WS_W1QT    (WS_XQ   + 4096*1024)     // 4 MB  w1^T swizzled [32][16][4][128][16]
#define WS_W2QT    (WS_W1QT + 4096*1024)     // 4 MB  w2^T swizzled [8][64][4][128][16]
#define WS_PS      (WS_W2QT + 4096*1024)     // 16 MB plane_s swizzled [32][64][4][128][16]
#define WS_PH      (WS_PS   + 4096*4096)     // 16 MB plane_h

__device__ __forceinline__ void async16(const void* g, void* l) {
  __builtin_amdgcn_global_load_lds(
      (const __attribute__((address_space(1))) unsigned*)g,
      (__attribute__((address_space(3))) unsigned*)l, 16, 0, 0);
}

// block-wide absmax over p0[0..n0) and optional p1[0..n1); bit-exact in any order
__device__ __forceinline__ float block_absmax(const float* __restrict__ p0, int n0,
                                              const float* __restrict__ p1, int n1,
                                              float* red, float* slot) {
  int tid = threadIdx.x, nt = blockDim.x;
  float m = 0.f;
  for (int i = tid; i < n0; i += nt) m = fmaxf(m, fabsf(p0[i]));
  if (p1) for (int i = tid; i < n1; i += nt) m = fmaxf(m, fabsf(p1[i]));
  for (int off = 32; off; off >>= 1) m = fmaxf(m, __shfl_down(m, off));
  if ((tid & 63) == 0) red[tid >> 6] = m;
  __syncthreads();
  if (tid == 0) {
    int nw = nt >> 6;
    float M = red[0];
    for (int w = 1; w < nw; w++) M = fmaxf(M, red[w]);
    *slot = M;
  }
  __syncthreads();
  return *slot;
}

// ---------------- abs-max partials over x, w1f, w2f ----------------
__global__ void k_absmax3(const float* __restrict__ x, const float* __restrict__ w1,
                          const float* __restrict__ w2, float* __restrict__ part) {
  int seg = blockIdx.x >> 9;              // 0,1,2
  int b = blockIdx.x & 511;
  const float* p = (seg == 0) ? x : (seg == 1) ? w1 : w2;
  int i = b * 256 + threadIdx.x;
  float m = 0.f;
  #pragma unroll
  for (int it = 0; it < 8; it++) {
    f32x4 v = ((const f32x4*)p)[i + it * 131072];
    m = fmaxf(m, fmaxf(fmaxf(fabsf(v.x), fabsf(v.y)), fmaxf(fabsf(v.z), fabsf(v.w))));
  }
  for (int off = 32; off; off >>= 1) m = fmaxf(m, __shfl_down(m, off));
  __shared__ float red[4];
  if ((threadIdx.x & 63) == 0) red[threadIdx.x >> 6] = m;
  __syncthreads();
  if (threadIdx.x == 0)
    part[blockIdx.x] = fmaxf(fmaxf(red[0], red[1]), fmaxf(red[2], red[3]));
}

// ---------------- quantize + transpose a weight matrix (inline body) ----------------
__device__ __forceinline__ void quantT_body(const float* __restrict__ w, float s,
                                            i32x4* __restrict__ out, int C, int tkbits,
                                            int b) {
  int L = b * 256 + threadIdx.x;
  int h_in = L & 127;
  int kb = (L >> 7) & 3;
  int tk = (L >> 9) & ((1 << tkbits) - 1);
  int hblk = L >> (9 + tkbits);
  int h = hblk * 128 + h_in;
  int k0 = (tk * 4 + kb) * 16;
  int wd[4];
  #pragma unroll
  for (int d = 0; d < 4; d++) {
    unsigned acc = 0;
    #pragma unroll
    for (int j = 0; j < 4; j++) {
      float v = w[(size_t)(k0 + d * 4 + j) * C + h];
      int q = (int)rintf(v / s) & 255;
      acc |= (unsigned)q << (8 * j);
    }
    wd[d] = (int)acc;
  }
  i32x4 o; o.x = wd[0]; o.y = wd[1]; o.z = wd[2]; o.w = wd[3];
  out[L] = o;
}

// ---------------- fused prep: quant_x + quantT(w1) + quantT(w2) + scale handoff ----------------
__global__ void k_prep(const float* __restrict__ x, const float* __restrict__ w1f,
                       const float* __restrict__ w2f, const float* __restrict__ b1f,
                       const float* __restrict__ b2f, const float* __restrict__ part,
                       float* __restrict__ scales,
                       i32x4* __restrict__ xq, i32x4* __restrict__ w1qt,
                       i32x4* __restrict__ w2qt) {
  __shared__ float red[4];
  __shared__ float slot;
  int seg = blockIdx.x >> 10;             // block-uniform
  int b = blockIdx.x & 1023;
  if (seg == 0) {
    float s = block_absmax(part, 512, nullptr, 0, red, &slot) / 127.0f;
    if (b == 0 && threadIdx.x == 0) scales[0] = s;   // handoff (bit-identical everywhere)
    int L = b * 256 + threadIdx.x;
    int m_in = L & 127, kb = (L >> 7) & 3, tk = (L >> 9) & 15, mblk = L >> 13;
    int m = mblk * 128 + m_in;
    int k0 = (tk * 4 + kb) * 16;
    const f32x4* px = (const f32x4*)(x + m * 1024 + k0);
    int wd[4];
    #pragma unroll
    for (int d = 0; d < 4; d++) {
      f32x4 v = px[d];
      int b0 = (int)rintf(v.x / s) & 255;
      int b1 = (int)rintf(v.y / s) & 255;
      int b2 = (int)rintf(v.z / s) & 255;
      int b3 = (int)rintf(v.w / s) & 255;
      wd[d] = b0 | (b1 << 8) | (b2 << 16) | (b3 << 24);
    }
    i32x4 o; o.x = wd[0]; o.y = wd[1]; o.z = wd[2]; o.w = wd[3];
    xq[L] = o;
  } else if (seg == 1) {
    float s = block_absmax(part + 512, 512, b1f, 4096, red, &slot) / 127.0f;
    if (b == 0 && threadIdx.x == 0) scales[1] = s;
    quantT_body(w1f, s, w1qt, 4096, 4, b);
  } else {
    float s = block_absmax(part + 1024, 512, b2f, 1024, red, &slot) / 127.0f;
    if (b == 0 && threadIdx.x == 0) scales[2] = s;
    quantT_body(w2f, s, w2qt, 1024, 6, b);
  }
}

// ---------------- GEMM1 v3: 1-wave blocks, LDS/barrier-free, scales from prep ----------------
// (unchanged; round-9 verified)
__launch_bounds__(64)
__global__ void k_gemm1(const i32x4* __restrict__ Aq, const i32x4* __restrict__ Bq,
                        const float* __restrict__ scales, const float* __restrict__ b1f,
                        unsigned* __restrict__ plane_s, unsigned* __restrict__ plane_h) {
  int lane = threadIdx.x;               // 0..63
  int bb = blockIdx.x;                  // batch block, 0..31
  int hb = blockIdx.y;                  // H block,     0..31
  int wid = blockIdx.z;                 // 0..3 (was wave id)
  int wm = wid & 1, wn = wid >> 1;
  int g = lane >> 4, l15 = lane & 15;

  const i32x4* gA = Aq + (size_t)hb * 16 * 512;
  const i32x4* gB = Bq + (size_t)bb * 16 * 512;
  int aoff = g * 128 + wm * 64 + l15;   // + r*16
  int boff = g * 128 + wn * 64 + l15;   // + c*16

  float sx  = scales[0];
  float s1v = scales[1];
  float mult1 = sx * s1v / s1v;         // exact f32 expr as reference

  i32x4 acc[4][4];
  #pragma unroll
  for (int r = 0; r < 4; r++)
    #pragma unroll
    for (int c = 0; c < 4; c++) acc[r][c] = (i32x4)(0);

  // prologue: frags for t=0
  i32x4 af[4], bf[4];
  #pragma unroll
  for (int r = 0; r < 4; r++) af[r] = gA[aoff + r * 16];
  #pragma unroll
  for (int c = 0; c < 4; c++) bf[c] = gB[boff + c * 16];

  for (int t = 0; t < 15; ++t) {
    i32x4 an[4], bn[4];
    const i32x4* ga = gA + (t + 1) * 512;
    const i32x4* gb = gB + (t + 1) * 512;
    #pragma unroll
    for (int r = 0; r < 4; r++) an[r] = ga[aoff + r * 16];
    #pragma unroll
    for (int c = 0; c < 4; c++) bn[c] = gb[boff + c * 16];
    #pragma unroll
    for (int r = 0; r < 4; r++)
      #pragma unroll
      for (int c = 0; c < 4; c++)
        acc[r][c] = __builtin_amdgcn_mfma_i32_16x16x64_i8(af[r], bf[c], acc[r][c], 0, 0, 0);
    #pragma unroll
    for (int r = 0; r < 4; r++) { af[r] = an[r]; bf[r] = bn[r]; }
  }
  #pragma unroll
  for (int r = 0; r < 4; r++)
    #pragma unroll
    for (int c = 0; c < 4; c++)
      acc[r][c] = __builtin_amdgcn_mfma_i32_16x16x64_i8(af[r], bf[c], acc[r][c], 0, 0, 0);

  int t2base = hb * 2 + wm;
  #pragma unroll
  for (int r = 0; r < 4; r++) {
    int hloc = wm * 64 + r * 16 + 4 * g;
    // per-lane bias requant (was LDS b1s[]) — same rintf(b1f/s1v) values
    int bq0 = (int)rintf(b1f[hb * 128 + hloc + 0] / s1v);
    int bq1 = (int)rintf(b1f[hb * 128 + hloc + 1] / s1v);
    int bq2 = (int)rintf(b1f[hb * 128 + hloc + 2] / s1v);
    int bq3 = (int)rintf(b1f[hb * 128 + hloc + 3] / s1v);
    #pragma unroll
    for (int c = 0; c < 4; c++) {
      unsigned lo = 0, hi = 0;
      #pragma unroll
      for (int q = 0; q < 4; q++) {
        int y0 = acc[r][c][q];
        int bqv = (q == 0) ? bq0 : (q == 1) ? bq1 : (q == 2) ? bq2 : bq3;
        int o = (short)((int)rintf((float)y0 * mult1) + bqv);    // int16 semantics
        int a = o > 0 ? o : 0;                                   // relu
        int s8 = (int)(signed char)(a & 0xFF);
        int h8 = (a >> 8) + (s8 < 0 ? 1 : 0);                    // a = 256*h8 + s8
        lo |= (unsigned)(s8 & 0xFF) << (8 * q);
        hi |= (unsigned)(h8 & 0xFF) << (8 * q);
      }
      int m_in = wn * 64 + c * 16 + l15;
      unsigned idx = (((unsigned)(bb * 64 + t2base) * 512u + (unsigned)(r * 128 + m_in)) << 2) + g;
      plane_s[idx] = lo;
      plane_h[idx] = hi;
    }
  }
}

// ---------------- GEMM2 v6b: counted vmcnt(4) across raw barriers, order-pinned ----------------
// v5 measured 46 us: __syncthreads' implicit vmcnt(0) drained B-reg loads + A staging
// every step (~2100 cyc exposed). v6: wait only the A pair at the barrier; B loads fly
// across. v6b hardening: sched_barrier(0) pins guarantee VMEM queue order [A x2, B x4]
// so vmcnt(4) provably retires exactly the A staging (compiler may not hoist B loads
// above the async16 calls — WAR on bf only pins them below the MFMAs).
__launch_bounds__(512, 4)
__global__ void k_gemm2(const i32x4* __restrict__ Ps, const i32x4* __restrict__ Ph,
                        const i32x4* __restrict__ Bq, const float* __restrict__ scales,
                        const float* __restrict__ b2f, float* __restrict__ out) {
  __shared__ i32x4 st[2048];   // 32 KB: [kh][buf][ AsS 0-255 | AsH 256-511 ]

  int tid = threadIdx.x;
  int L = blockIdx.x;
  int mb = ((L & 7) << 3) | ((L >> 3) & 7);   // same mb -> same XCD (A-strip L2 reuse)
  int nb = L >> 6;                             // 0..7
  int mblk = mb >> 1, half = mb & 1;
  int wid = tid >> 6, lane = tid & 63;
  int kh = wid >> 2, w2 = wid & 3;
  int wm = w2 & 1, wn = w2 >> 1;
  int g = lane >> 4, l15 = lane & 15;
  int t256 = tid & 255;
  int sbase = kh * 1024;
  int a_idx = (t256 >> 6) * 128 + half * 64 + (t256 & 63);
  int b_idx = g * 128 + wn * 64 + l15;         // + c*16 within B chunk

  // prologue: stage tile 0 A-planes + load B(0) regs
  {
    int t = kh * 32;
    const i32x4* pS = Ps + ((size_t)(mblk * 64 + t) << 9);
    const i32x4* pH = Ph + ((size_t)(mblk * 64 + t) << 9);
    async16(pS + a_idx, &st[sbase + t256]);
    async16(pH + a_idx, &st[sbase + 256 + t256]);
  }
  i32x4 bf[4];
  {
    const i32x4* pB = Bq + ((size_t)(nb * 64 + kh * 32) << 9);
    #pragma unroll
    for (int c = 0; c < 4; c++) bf[c] = pB[b_idx + c * 16];
  }

  // scales from prep handoff (bit-identical); replaces two absmax scans
  float s1v = scales[1];
  float s2v = scales[2];
  float mult2 = s1v * s2v / s2v;   // exact f32 expr as reference
  int bq[4];
  #pragma unroll
  for (int c = 0; c < 4; c++)
    bq[c] = (int)rintf(b2f[nb * 128 + wn * 64 + c * 16 + l15] / s2v);

  i32x4 accS[2][4], accH[2][4];
  #pragma unroll
  for (int r = 0; r < 2; r++)
    #pragma unroll
    for (int c = 0; c < 4; c++) { accS[r][c] = (i32x4)(0); accH[r][c] = (i32x4)(0); }

  __syncthreads();   // one full drain: tile-0 staging globally visible

  for (int tt = 0; tt < 32; ++tt) {
    int cur = tt & 1;
    // issue A(tt+1) staging first (must be OLDEST in the VMEM queue this iter)
    if (tt + 1 < 32) {
      int t = kh * 32 + tt + 1;
      const i32x4* pS = Ps + ((size_t)(mblk * 64 + t) << 9);
      const i32x4* pH = Ph + ((size_t)(mblk * 64 + t) << 9);
      int R1 = sbase + (cur ^ 1) * 512;
      async16(pS + a_idx, &st[R1 + t256]);
      async16(pH + a_idx, &st[R1 + 256 + t256]);
      __builtin_amdgcn_sched_barrier(0);   // pin: nothing below may hoist above A staging
    }
    int R = sbase + cur * 512;
    i32x4 aS[2], aH[2];
    #pragma unroll
    for (int r = 0; r < 2; r++) {
      aS[r] = st[R + g * 64 + wm * 32 + r * 16 + l15];
      aH[r] = st[R + 256 + g * 64 + wm * 32 + r * 16 + l15];
    }
    #pragma unroll
    for (int r = 0; r < 2; r++)
      #pragma unroll
      for (int c = 0; c < 4; c++) {
        accS[r][c] = __builtin_amdgcn_mfma_i32_16x16x64_i8(aS[r], bf[c], accS[r][c], 0, 0, 0);
        accH[r][c] = __builtin_amdgcn_mfma_i32_16x16x64_i8(aH[r], bf[c], accH[r][c], 0, 0, 0);
      }
    if (tt + 1 < 32) {
      __builtin_amdgcn_sched_barrier(0);   // pin: B loads stay below (queue order A then B)
      // B(tt+1) regs cross the barrier in flight; compiler counted-waits before next use
      const i32x4* pB = Bq + ((size_t)(nb * 64 + kh * 32 + tt + 1) << 9);
      #pragma unroll
      for (int c = 0; c < 4; c++) bf[c] = pB[b_idx + c * 16];
      // outstanding (pinned order): A(tt+1) x2 then B(tt+1) x4 -> wait the A pair only
      asm volatile("s_waitcnt vmcnt(4)" ::: "memory");
      __builtin_amdgcn_s_barrier();
      __builtin_amdgcn_sched_barrier(0);   // pin: next tile's ds_reads stay below barrier
    }
  }

  // combine planes within this k-half (exact mod 2^32)
  int y0p[2][4][4];
  #pragma unroll
  for (int r = 0; r < 2; r++)
    #pragma unroll
    for (int c = 0; c < 4; c++)
      #pragma unroll
      for (int q = 0; q < 4; q++)
        y0p[r][c][q] = accS[r][c][q] + accH[r][c][q] * 256;

  __syncthreads();                 // staging LDS now dead; reuse as merge buffer
  int* mg = (int*)st;              // 32 KB: [idx32][t256]
  if (kh == 1) {
    #pragma unroll
    for (int r = 0; r < 2; r++)
      #pragma unroll
      for (int c = 0; c < 4; c++)
        #pragma unroll
        for (int q = 0; q < 4; q++)
          mg[((r * 4 + c) * 4 + q) * 256 + t256] = y0p[r][c][q];
  }
  __syncthreads();
  if (kh == 0) {
    #pragma unroll
    for (int r = 0; r < 2; r++) {
      int m0 = mb * 64 + wm * 32 + r * 16 + 4 * g;
      #pragma unroll
      for (int c = 0; c < 4; c++) {
        int n = nb * 128 + wn * 64 + c * 16 + l15;
        #pragma unroll
        for (int q = 0; q < 4; q++) {
          int y0 = y0p[r][c][q] + mg[((r * 4 + c) * 4 + q) * 256 + t256];
          int o = (short)((int)rintf((float)y0 * mult2) + bq[c]);   // int16 semantics
          out[(size_t)(m0 + q) * 1024 + n] = (float)o * s2v;
        }
      }
    }
  }
}

extern "C" void kernel_launch(void* const* d_in, const int* in_sizes, int n_in,
                              void* d_out, int out_size, void* d_ws, size_t ws_size,
                              hipStream_t stream) {
  const float* x   = (const float*)d_in[0];
  const float* w1f = (const float*)d_in[1];
  const float* b1f = (const float*)d_in[2];
  const float* w2f = (const float*)d_in[3];
  const float* b2f = (const float*)d_in[4];
  float* out = (float*)d_out;

  char* ws = (char*)d_ws;
  float*  part    = (float*)(ws + WS_PART);
  float*  scales  = part + 1536;
  i32x4*  xq      = (i32x4*)(ws + WS_XQ);
  i32x4*  w1qt    = (i32x4*)(ws + WS_W1QT);
  i32x4*  w2qt    = (i32x4*)(ws + WS_W2QT);
  unsigned* ps    = (unsigned*)(ws + WS_PS);
  unsigned* ph    = (unsigned*)(ws + WS_PH);

  k_absmax3<<<1536, 256, 0, stream>>>(x, w1f, w2f, part);
  k_prep<<<3072, 256, 0, stream>>>(x, w1f, w2f, b1f, b2f, part, scales, xq, w1qt, w2qt);
  k_gemm1<<<dim3(32, 32, 4), 64, 0, stream>>>(w1qt, xq, scales, b1f, ps, ph);
  k_gemm2<<<512, 512, 0, stream>>>((const i32x4*)ps, (const i32x4*)ph, w2qt,
                                   scales, b2f, out);
}